// Round 2
// baseline (438.444 us; speedup 1.0000x reference)
//
#include <hip/hip_runtime.h>
#include <hip/hip_bf16.h>

#define NN 10000
#define KK 32
#define DDIRIN 10
#define DDIR 64
#define DD 128   // D_DIST == D_DIST_IN == D_ATOM == 128

__device__ __forceinline__ float silu_f(float x) { return x / (1.0f + __expf(-x)); }

// One block (256 threads) per node. All float tensors are float32.
// out[n, 0:128]   = masked-mean_k silu(edist[n,k,:] @ dW + db)
// out[n, 128:192] = masked-mean_k silu(nde[nl[n,k]] @ sW + sb)
// out[n, 192:320] = masked-mean_k src_emb[an[nl[n,k]]]
// out[n, 320:384] = silu(nde[n] @ tW + tb) * cnt/(cnt+1e-5)
// out[n, 384:512] = tgt_emb[an[n]] * cnt/(cnt+1e-5)
__global__ __launch_bounds__(256) void gnn_node_kernel(
    const int*   __restrict__ an,      // [N]
    const float* __restrict__ nde,     // [N,10]
    const float* __restrict__ edist,   // [N,32,128]
    const int*   __restrict__ nl,      // [N,32]
    const int*   __restrict__ nmask,   // [N,32]
    const float* __restrict__ semb,    // [100,128]
    const float* __restrict__ temb,    // [100,128]
    const float* __restrict__ sW, const float* __restrict__ sb,   // [10,64],[64]
    const float* __restrict__ tW, const float* __restrict__ tb,   // [10,64],[64]
    const float* __restrict__ dW, const float* __restrict__ db,   // [128,128],[128]
    float* __restrict__ out)           // [N,512]
{
    const int n = blockIdx.x;
    const int tid = threadIdx.x;

    __shared__ __align__(16) float s_eT[DD * 36];   // edist^T tile [i][k], k padded 32->36
    __shared__ float s_sd[KK][DDIR + 4];            // sender dir emb per neighbor
    __shared__ float s_td[DDIR];                    // receiver dir emb (this node)
    __shared__ float s_nde[KK][DDIRIN];             // gathered nde rows for neighbors
    __shared__ int   s_nl[KK];
    __shared__ float s_mask[KK];
    __shared__ int   s_annl[KK];
    __shared__ float s_red[4 * DD];

    if (tid < KK) {
        int j = nl[n * KK + tid];
        s_nl[tid] = j;
        s_mask[tid] = (nmask[n * KK + tid] != 0) ? 1.0f : 0.0f;
        s_annl[tid] = an[j];
    }

    // Stage edist row (32x128 f32 = 16 KB) transposed into LDS.
    // Writes: addr = i*36+k; within a half-wave k=0..31 covers 32 distinct banks;
    // the two halves alias 2-way (free).
    {
        const float4* E4 = reinterpret_cast<const float4*>(edist + (size_t)n * (KK * DD));
        int k  = tid & 31;
        int cg = tid >> 5;                 // 0..7
#pragma unroll
        for (int j = 0; j < 4; ++j) {
            int c = cg + 8 * j;            // float4 group along i (0..31)
            float4 v = E4[k * 32 + c];
            s_eT[(c * 4 + 0) * 36 + k] = v.x;
            s_eT[(c * 4 + 1) * 36 + k] = v.y;
            s_eT[(c * 4 + 2) * 36 + k] = v.z;
            s_eT[(c * 4 + 3) * 36 + k] = v.w;
        }
    }
    __syncthreads();   // s_nl/s_mask/s_annl + s_eT ready

    // Gather neighbor nde rows (32 x 10 f32)
    for (int idx = tid; idx < KK * DDIRIN; idx += 256) {
        int k = idx / DDIRIN, i = idx - k * DDIRIN;
        s_nde[k][i] = nde[s_nl[k] * DDIRIN + i];
    }
    __syncthreads();   // s_nde ready

    // Sender-dir MLP for the 32 neighbors: thread -> (k = tid>>3, dims (tid&7)*8..+7)
    {
        int k  = tid >> 3;
        int d0 = (tid & 7) * 8;
        float acc[8];
#pragma unroll
        for (int d = 0; d < 8; ++d) acc[d] = sb[d0 + d];
#pragma unroll
        for (int i = 0; i < DDIRIN; ++i) {
            float x = s_nde[k][i];   // 8-lane broadcast per k
#pragma unroll
            for (int d = 0; d < 8; ++d)
                acc[d] = fmaf(x, sW[i * DDIR + d0 + d], acc[d]);
        }
#pragma unroll
        for (int d = 0; d < 8; ++d) s_sd[k][d0 + d] = silu_f(acc[d]);
    }
    // Receiver-dir MLP for this node
    if (tid < DDIR) {
        float a = tb[tid];
        const float* x = nde + n * DDIRIN;
#pragma unroll
        for (int i = 0; i < DDIRIN; ++i)
            a = fmaf(x[i], tW[i * DDIR + tid], a);
        s_td[tid] = silu_f(a);
    }
    __syncthreads();   // s_sd, s_td ready

    float cnt = 0.0f;
#pragma unroll
    for (int k = 0; k < KK; ++k) cnt += s_mask[k];
    const float inv = 1.0f / (cnt + 1e-5f);
    const float self_scale = cnt * inv;

    float* outn = out + (size_t)n * 512;

    // ---- dims 128..512 (wave-uniform branches) ----
    if (tid < 64) {
        float s = 0.0f;
#pragma unroll
        for (int k = 0; k < KK; ++k)
            s += s_mask[k] * s_sd[k][tid];
        outn[128 + tid] = s * inv;
    } else if (tid < 192) {
        int d = tid - 64;
        float s = 0.0f;
#pragma unroll 4
        for (int k = 0; k < KK; ++k)
            s += s_mask[k] * semb[s_annl[k] * DD + d];
        outn[192 + d] = s * inv;
    } else {
        int d = tid - 192;
        outn[320 + d] = s_td[d] * self_scale;
    }
    if (tid < 128) {
        outn[384 + tid] = temb[an[n] * DD + tid] * self_scale;
    }

    // ---- dims 0..128: the 32x128 @ 128x128 GEMM, register tile 8 rows x 2 cols ----
    const int cg = tid & 63;       // column group -> dims d0, d0+1
    const int rg = tid >> 6;       // row group   -> edges rg*8 .. rg*8+7 (wave-uniform)
    const int d0 = cg * 2;
    float acc[16];
#pragma unroll
    for (int r = 0; r < 16; ++r) acc[r] = 0.0f;
    const float* eTp = s_eT + rg * 8;
#pragma unroll 4
    for (int i = 0; i < DD; ++i) {
        float2 wv = *reinterpret_cast<const float2*>(dW + i * DD + d0);
        float w0 = wv.x, w1 = wv.y;
        float4 e0 = *reinterpret_cast<const float4*>(eTp + i * 36);      // rows 0..3 (LDS broadcast)
        float4 e1 = *reinterpret_cast<const float4*>(eTp + i * 36 + 4);  // rows 4..7
        acc[0]  = fmaf(e0.x, w0, acc[0]);   acc[1]  = fmaf(e0.x, w1, acc[1]);
        acc[2]  = fmaf(e0.y, w0, acc[2]);   acc[3]  = fmaf(e0.y, w1, acc[3]);
        acc[4]  = fmaf(e0.z, w0, acc[4]);   acc[5]  = fmaf(e0.z, w1, acc[5]);
        acc[6]  = fmaf(e0.w, w0, acc[6]);   acc[7]  = fmaf(e0.w, w1, acc[7]);
        acc[8]  = fmaf(e1.x, w0, acc[8]);   acc[9]  = fmaf(e1.x, w1, acc[9]);
        acc[10] = fmaf(e1.y, w0, acc[10]);  acc[11] = fmaf(e1.y, w1, acc[11]);
        acc[12] = fmaf(e1.z, w0, acc[12]);  acc[13] = fmaf(e1.z, w1, acc[13]);
        acc[14] = fmaf(e1.w, w0, acc[14]);  acc[15] = fmaf(e1.w, w1, acc[15]);
    }

    // silu + mask + partial sum over this wave's 8 rows
    float b0 = db[d0];
    float b1 = db[d0 + 1];
    float p0 = 0.0f, p1 = 0.0f;
#pragma unroll
    for (int r = 0; r < 8; ++r) {
        float m = s_mask[rg * 8 + r];
        p0 += m * silu_f(acc[2 * r]     + b0);
        p1 += m * silu_f(acc[2 * r + 1] + b1);
    }
    s_red[rg * DD + d0]     = p0;
    s_red[rg * DD + d0 + 1] = p1;
    __syncthreads();
    if (rg == 0) {
        float t0 = s_red[d0]     + s_red[DD + d0]     + s_red[2 * DD + d0]     + s_red[3 * DD + d0];
        float t1 = s_red[d0 + 1] + s_red[DD + d0 + 1] + s_red[2 * DD + d0 + 1] + s_red[3 * DD + d0 + 1];
        outn[d0]     = t0 * inv;
        outn[d0 + 1] = t1 * inv;
    }
}

extern "C" void kernel_launch(void* const* d_in, const int* in_sizes, int n_in,
                              void* d_out, int out_size, void* d_ws, size_t ws_size,
                              hipStream_t stream) {
    const int*   an    = (const int*)  d_in[0];
    const float* nde   = (const float*)d_in[1];
    const float* edist = (const float*)d_in[2];
    const int*   nl    = (const int*)  d_in[3];
    const int*   nmask = (const int*)  d_in[4];
    const float* semb  = (const float*)d_in[5];
    const float* temb  = (const float*)d_in[6];
    const float* sW    = (const float*)d_in[7];
    const float* sb    = (const float*)d_in[8];
    const float* tW    = (const float*)d_in[9];
    const float* tb    = (const float*)d_in[10];
    const float* dW    = (const float*)d_in[11];
    const float* db    = (const float*)d_in[12];
    float* out = (float*)d_out;

    gnn_node_kernel<<<NN, 256, 0, stream>>>(an, nde, edist, nl, nmask, semb, temb,
                                            sW, sb, tW, tb, dW, db, out);
}

// Round 3
// 304.773 us; speedup vs baseline: 1.4386x; 1.4386x over previous
//
#include <hip/hip_runtime.h>
#include <hip/hip_bf16.h>

#define NN 10000
#define KK 32
#define DDIRIN 10
#define DDIR 64
#define DD 128          // D_DIST == D_DIST_IN == D_ATOM == 128
#define NODE_BLOCKS 2500

typedef short bf16x8 __attribute__((ext_vector_type(8)));
typedef float f32x4  __attribute__((ext_vector_type(4)));

__device__ __forceinline__ float silu_f(float x) { return x / (1.0f + __expf(-x)); }

// f32 -> bf16 (RNE) as raw short
__device__ __forceinline__ short f2bf(float f) {
    union { float f; unsigned u; } v; v.f = f;
    unsigned r = (v.u + 0x7fffu + ((v.u >> 16) & 1u)) >> 16;
    return (short)r;
}

// ---- Kernel 1 (ws path): per-node direction MLPs (10 -> 64, x2), fp32 out ----
__global__ __launch_bounds__(256) void dir_kernel(
    const float* __restrict__ nde,
    const float* __restrict__ sW, const float* __restrict__ sb,
    const float* __restrict__ tW, const float* __restrict__ tb,
    float* __restrict__ sd, float* __restrict__ td)
{
    int gid = blockIdx.x * 256 + threadIdx.x;
    if (gid >= NN * DDIR) return;
    int n = gid >> 6, d = gid & 63;
    float a = sb[d], t = tb[d];
    const float* x = nde + n * DDIRIN;
#pragma unroll
    for (int i = 0; i < DDIRIN; ++i) {
        float xv = x[i];
        a = fmaf(xv, sW[i * DDIR + d], a);
        t = fmaf(xv, tW[i * DDIR + d], t);
    }
    sd[gid] = silu_f(a);
    td[gid] = silu_f(t);
}

// ---- Kernel 2: persistent blocks, 4 nodes each. MFMA GEMM for dims 0..128. ----
// s_E layout: 32 rows x 16 col-blocks of 8 bf16 (16B); block cb stored at cb ^ (row&7).
// This makes both staging ds_write_b128 and A-fragment ds_read_b128 hit the
// contiguous-lane bank pattern (conflict-free for b128).
template<bool USE_WS>
__global__ __launch_bounds__(256) void gnn_mfma_kernel(
    const int*   __restrict__ an,      // [N]
    const float* __restrict__ nde,     // [N,10]
    const float* __restrict__ edist,   // [N,32,128]
    const int*   __restrict__ nl,      // [N,32]
    const int*   __restrict__ nmask,   // [N,32]
    const float* __restrict__ semb,    // [100,128]
    const float* __restrict__ temb,    // [100,128]
    const float* __restrict__ sW, const float* __restrict__ sb,
    const float* __restrict__ tW, const float* __restrict__ tb,
    const float* __restrict__ dW, const float* __restrict__ db,   // [128,128],[128]
    const float* __restrict__ sd_ws,   // [N,64] or null
    const float* __restrict__ td_ws,   // [N,64] or null
    float* __restrict__ out)           // [N,512]
{
    const int tid  = threadIdx.x;
    const int wid  = tid >> 6;       // wave 0..3 -> output cols [32*wid, 32*wid+32)
    const int lane = tid & 63;
    const int l15  = lane & 15;
    const int quad = lane >> 4;

    __shared__ __align__(16) short s_E[32 * 128];   // 8 KB, swizzled bf16 E-tile
    __shared__ int   s_nl[KK];
    __shared__ float s_mask[KK];
    __shared__ int   s_annl[KK];
    // fallback-only LDS (size 1 when unused)
    __shared__ float s_sd[USE_WS ? 1 : KK * (DDIR + 4)];
    __shared__ float s_nde[USE_WS ? 1 : KK * DDIRIN];
    __shared__ float s_td[DDIR];

    // ---- B fragments: W cvt'd to bf16, held in registers for the whole block ----
    // B[k][n] fragment: lane holds k = t*32 + quad*8 + j, n = (2*wid+c2)*16 + l15
    bf16x8 bfrag[2][4];
    float  bias[2];
#pragma unroll
    for (int c2 = 0; c2 < 2; ++c2) {
        int ncol = (2 * wid + c2) * 16 + l15;
        bias[c2] = db[ncol];
#pragma unroll
        for (int t = 0; t < 4; ++t) {
            bf16x8 v;
#pragma unroll
            for (int j = 0; j < 8; ++j)
                v[j] = f2bf(dW[(t * 32 + quad * 8 + j) * DD + ncol]);
            bfrag[c2][t] = v;
        }
    }

    for (int n = blockIdx.x; n < NN; n += NODE_BLOCKS) {
        __syncthreads();   // previous iteration's LDS consumers done

        if (tid < KK) {
            int j = nl[n * KK + tid];
            s_nl[tid]   = j;
            s_mask[tid] = (nmask[n * KK + tid] != 0) ? 1.0f : 0.0f;
            s_annl[tid] = an[j];
        }
        // stage edist row (32x128 f32) -> bf16 swizzled LDS; thread: 16 consecutive f32
        {
            const float4* E4 = reinterpret_cast<const float4*>(edist + (size_t)n * (KK * DD));
            int row = tid >> 3;             // 0..31
            int cb0 = (tid & 7) * 2;        // col-block pair
            float4 a = E4[tid * 4 + 0], b = E4[tid * 4 + 1];
            float4 c = E4[tid * 4 + 2], d = E4[tid * 4 + 3];
            bf16x8 v0, v1;
            v0[0] = f2bf(a.x); v0[1] = f2bf(a.y); v0[2] = f2bf(a.z); v0[3] = f2bf(a.w);
            v0[4] = f2bf(b.x); v0[5] = f2bf(b.y); v0[6] = f2bf(b.z); v0[7] = f2bf(b.w);
            v1[0] = f2bf(c.x); v1[1] = f2bf(c.y); v1[2] = f2bf(c.z); v1[3] = f2bf(c.w);
            v1[4] = f2bf(d.x); v1[5] = f2bf(d.y); v1[6] = f2bf(d.z); v1[7] = f2bf(d.w);
            int sw0 = (cb0     ) ^ (row & 7);
            int sw1 = (cb0 + 1 ) ^ (row & 7);
            *reinterpret_cast<bf16x8*>(&s_E[row * 128 + sw0 * 8]) = v0;
            *reinterpret_cast<bf16x8*>(&s_E[row * 128 + sw1 * 8]) = v1;
        }
        __syncthreads();   // s_nl/s_mask/s_annl + s_E ready

        float cnt = 0.0f;
#pragma unroll
        for (int k = 0; k < KK; ++k) cnt += s_mask[k];
        const float inv = 1.0f / (cnt + 1e-5f);
        const float self_scale = cnt * inv;
        float* outn = out + (size_t)n * 512;

        // ---- MFMA GEMM: C[32 edges x 128 dims] = E @ W ----
        bf16x8 afrag[2][4];
#pragma unroll
        for (int rt = 0; rt < 2; ++rt)
#pragma unroll
            for (int t = 0; t < 4; ++t) {
                int r  = rt * 16 + l15;                 // edge row
                int cb = (t * 4 + quad) ^ (l15 & 7);    // swizzled col-block
                afrag[rt][t] = *reinterpret_cast<const bf16x8*>(&s_E[r * 128 + cb * 8]);
            }
        f32x4 acc[2][2] = {{{0.f,0.f,0.f,0.f},{0.f,0.f,0.f,0.f}},
                           {{0.f,0.f,0.f,0.f},{0.f,0.f,0.f,0.f}}};
#pragma unroll
        for (int t = 0; t < 4; ++t)
#pragma unroll
            for (int rt = 0; rt < 2; ++rt) {
                acc[rt][0] = __builtin_amdgcn_mfma_f32_16x16x32_bf16(afrag[rt][t], bfrag[0][t], acc[rt][0], 0, 0, 0);
                acc[rt][1] = __builtin_amdgcn_mfma_f32_16x16x32_bf16(afrag[rt][t], bfrag[1][t], acc[rt][1], 0, 0, 0);
            }

        // epilogue: silu + mask + sum over 32 edges. D layout: col=l15, row=quad*4+reg (+16*rt)
#pragma unroll
        for (int c2 = 0; c2 < 2; ++c2) {
            float p = 0.0f;
#pragma unroll
            for (int rt = 0; rt < 2; ++rt)
#pragma unroll
                for (int rg = 0; rg < 4; ++rg)
                    p += s_mask[rt * 16 + quad * 4 + rg] * silu_f(acc[rt][c2][rg] + bias[c2]);
            p += __shfl_xor(p, 16);
            p += __shfl_xor(p, 32);
            if (quad == c2) outn[(2 * wid + c2) * 16 + l15] = p * inv;
        }

        // ---- fallback: in-kernel direction MLPs ----
        if constexpr (!USE_WS) {
            for (int idx = tid; idx < KK * DDIRIN; idx += 256) {
                int k = idx / DDIRIN, i = idx - k * DDIRIN;
                s_nde[k * DDIRIN + i] = nde[s_nl[k] * DDIRIN + i];
            }
            __syncthreads();
            {
                int k = tid >> 3, d0 = (tid & 7) * 8;
                float a8[8];
#pragma unroll
                for (int d = 0; d < 8; ++d) a8[d] = sb[d0 + d];
#pragma unroll
                for (int i = 0; i < DDIRIN; ++i) {
                    float x = s_nde[k * DDIRIN + i];
#pragma unroll
                    for (int d = 0; d < 8; ++d)
                        a8[d] = fmaf(x, sW[i * DDIR + d0 + d], a8[d]);
                }
#pragma unroll
                for (int d = 0; d < 8; ++d) s_sd[k * (DDIR + 4) + d0 + d] = silu_f(a8[d]);
            }
            if (tid < DDIR) {
                float a = tb[tid];
#pragma unroll
                for (int i = 0; i < DDIRIN; ++i)
                    a = fmaf(nde[n * DDIRIN + i], tW[i * DDIR + tid], a);
                s_td[tid] = silu_f(a);
            }
            __syncthreads();
        }

        // ---- dims 128..512 ----
        if (tid < 64) {
            float s = 0.0f;
            if constexpr (USE_WS) {
#pragma unroll 4
                for (int k = 0; k < KK; ++k)
                    s += s_mask[k] * sd_ws[s_nl[k] * DDIR + tid];
            } else {
#pragma unroll
                for (int k = 0; k < KK; ++k)
                    s += s_mask[k] * s_sd[k * (DDIR + 4) + tid];
            }
            outn[128 + tid] = s * inv;
        } else if (tid < 192) {
            int d = tid - 64;
            float s = 0.0f;
#pragma unroll 4
            for (int k = 0; k < KK; ++k)
                s += s_mask[k] * semb[s_annl[k] * DD + d];
            outn[192 + d] = s * inv;
        } else {
            int d = tid - 192;
            float tdv;
            if constexpr (USE_WS) tdv = td_ws[n * DDIR + d];
            else                  tdv = s_td[d];
            outn[320 + d] = tdv * self_scale;
        }
        if (tid < 128)
            outn[384 + tid] = temb[an[n] * DD + tid] * self_scale;
    }
}

extern "C" void kernel_launch(void* const* d_in, const int* in_sizes, int n_in,
                              void* d_out, int out_size, void* d_ws, size_t ws_size,
                              hipStream_t stream) {
    const int*   an    = (const int*)  d_in[0];
    const float* nde   = (const float*)d_in[1];
    const float* edist = (const float*)d_in[2];
    const int*   nl    = (const int*)  d_in[3];
    const int*   nmask = (const int*)  d_in[4];
    const float* semb  = (const float*)d_in[5];
    const float* temb  = (const float*)d_in[6];
    const float* sW    = (const float*)d_in[7];
    const float* sb    = (const float*)d_in[8];
    const float* tW    = (const float*)d_in[9];
    const float* tb    = (const float*)d_in[10];
    const float* dW    = (const float*)d_in[11];
    const float* db    = (const float*)d_in[12];
    float* out = (float*)d_out;

    const size_t need = (size_t)NN * DDIR * sizeof(float) * 2;   // 5.12 MB
    if (ws_size >= need) {
        float* sd = (float*)d_ws;
        float* td = sd + (size_t)NN * DDIR;
        dir_kernel<<<(NN * DDIR + 255) / 256, 256, 0, stream>>>(nde, sW, sb, tW, tb, sd, td);
        gnn_mfma_kernel<true><<<NODE_BLOCKS, 256, 0, stream>>>(
            an, nde, edist, nl, nmask, semb, temb, sW, sb, tW, tb, dW, db, sd, td, out);
    } else {
        gnn_mfma_kernel<false><<<NODE_BLOCKS, 256, 0, stream>>>(
            an, nde, edist, nl, nmask, semb, temb, sW, sb, tW, tb, dW, db,
            nullptr, nullptr, out);
    }
}

// Round 4
// 280.685 us; speedup vs baseline: 1.5620x; 1.0858x over previous
//
#include <hip/hip_runtime.h>
#include <hip/hip_bf16.h>

#define NN 10000
#define KK 32
#define DDIRIN 10
#define DDIR 64
#define DD 128          // D_DIST == D_DIST_IN == D_ATOM == 128

typedef short bf16x8 __attribute__((ext_vector_type(8)));
typedef float f32x4  __attribute__((ext_vector_type(4)));

__device__ __forceinline__ float silu_f(float x) { return x / (1.0f + __expf(-x)); }

// packed f32x2 -> bf16x2 (RNE) -> raw shorts
__device__ __forceinline__ ushort2 pk_bf16(float a, float b) {
    __hip_bfloat162 h = __float22bfloat162_rn(float2{a, b});
    union { __hip_bfloat162 h; ushort2 u; } v; v.h = h;
    return v.u;
}

// ---- Kernel 1 (ws path): per-node direction MLPs (10 -> 64, x2), fp32 out ----
__global__ __launch_bounds__(256) void dir_kernel(
    const float* __restrict__ nde,
    const float* __restrict__ sW, const float* __restrict__ sb,
    const float* __restrict__ tW, const float* __restrict__ tb,
    float* __restrict__ sd, float* __restrict__ td)
{
    int gid = blockIdx.x * 256 + threadIdx.x;
    if (gid >= NN * DDIR) return;
    int n = gid >> 6, d = gid & 63;
    float a = sb[d], t = tb[d];
    const float* x = nde + n * DDIRIN;
#pragma unroll
    for (int i = 0; i < DDIRIN; ++i) {
        float xv = x[i];
        a = fmaf(xv, sW[i * DDIR + d], a);
        t = fmaf(xv, tW[i * DDIR + d], t);
    }
    sd[gid] = silu_f(a);
    td[gid] = silu_f(t);
}

// ---- Kernel 2: dims 0..128. Single-shot, 4 nodes (=128 edge rows) per block. ----
// s_E: 128 rows x 16 kb-blocks of 8 bf16; block kb stored at kb ^ (row&7).
// Masked-off rows zeroed at staging; epilogue corrects with
//   sum_masked silu = sum_all silu - (32-cnt)*silu(bias).
__global__ __launch_bounds__(256, 2) void gemm_kernel(
    const float* __restrict__ edist,   // [N,32,128]
    const int*   __restrict__ nmask,   // [N,32]
    const float* __restrict__ dW,      // [128,128]
    const float* __restrict__ db,      // [128]
    float* __restrict__ out)           // [N,512]
{
    const int tid  = threadIdx.x;
    const int wid  = tid >> 6;       // wave -> output cols [32*wid, 32*wid+32)
    const int lane = tid & 63;
    const int l15  = lane & 15;
    const int quad = lane >> 4;
    const int n0   = blockIdx.x * 4;

    __shared__ __align__(16) short s_E[128 * 128];   // 32 KB bf16, swizzled
    __shared__ float s_cnt[4];

    // B fragments: dW cvt'd to bf16, in registers. lane: k = t*32+quad*8+j, n = ncol
    bf16x8 bfrag[2][4];
    float  bias[2];
#pragma unroll
    for (int c2 = 0; c2 < 2; ++c2) {
        int ncol = (2 * wid + c2) * 16 + l15;
        bias[c2] = db[ncol];
#pragma unroll
        for (int t = 0; t < 4; ++t) {
            bf16x8 v;
#pragma unroll
            for (int j2 = 0; j2 < 4; ++j2) {
                int k0 = t * 32 + quad * 8 + 2 * j2;
                ushort2 u = pk_bf16(dW[k0 * DD + ncol], dW[(k0 + 1) * DD + ncol]);
                v[2 * j2]     = (short)u.x;
                v[2 * j2 + 1] = (short)u.y;
            }
            bfrag[c2][t] = v;
        }
    }

    // Stage 4 edist rows (64 KB f32) -> bf16 LDS, zeroing masked rows.
    // Thread t, iter i: 8 consecutive f32 at float4-index f0=2t+512i
    //   -> row = f0>>5, kb = t&15 -> one ds_write_b128.
    {
        const float4* E4 = reinterpret_cast<const float4*>(edist + (size_t)n0 * (KK * DD));
        const int* nm = nmask + n0 * KK;
#pragma unroll
        for (int i = 0; i < 8; ++i) {
            int f0  = 2 * tid + 512 * i;
            int row = f0 >> 5;
            float4 a = E4[f0], b = E4[f0 + 1];
            ushort2 u0 = pk_bf16(a.x, a.y), u1 = pk_bf16(a.z, a.w);
            ushort2 u2 = pk_bf16(b.x, b.y), u3 = pk_bf16(b.z, b.w);
            bf16x8 v;
            v[0] = (short)u0.x; v[1] = (short)u0.y; v[2] = (short)u1.x; v[3] = (short)u1.y;
            v[4] = (short)u2.x; v[5] = (short)u2.y; v[6] = (short)u3.x; v[7] = (short)u3.y;
            bf16x8 z; 
#pragma unroll
            for (int q = 0; q < 8; ++q) z[q] = 0;
            v = (nm[row] != 0) ? v : z;
            int kb = tid & 15;
            int sw = kb ^ (row & 7);
            *reinterpret_cast<bf16x8*>(&s_E[row * 128 + sw * 8]) = v;
        }
        if (tid < 4) {
            int c = 0;
#pragma unroll 8
            for (int k = 0; k < KK; ++k) c += (nm[tid * KK + k] != 0) ? 1 : 0;
            s_cnt[tid] = (float)c;
        }
    }
    __syncthreads();   // the ONLY barrier

    // MFMA: C[128 rows x 128 cols]; wave owns 32 cols, all 8 row-tiles.
    f32x4 acc[8][2];
#pragma unroll
    for (int rt = 0; rt < 8; ++rt)
#pragma unroll
        for (int c2 = 0; c2 < 2; ++c2)
#pragma unroll
            for (int g = 0; g < 4; ++g) acc[rt][c2][g] = 0.0f;

#pragma unroll
    for (int rt = 0; rt < 8; ++rt) {
        bf16x8 af[4];
        int r = rt * 16 + l15;
#pragma unroll
        for (int t = 0; t < 4; ++t) {
            int kb = (4 * t + quad) ^ (l15 & 7);
            af[t] = *reinterpret_cast<const bf16x8*>(&s_E[r * 128 + kb * 8]);
        }
#pragma unroll
        for (int t = 0; t < 4; ++t) {
            acc[rt][0] = __builtin_amdgcn_mfma_f32_16x16x32_bf16(af[t], bfrag[0][t], acc[rt][0], 0, 0, 0);
            acc[rt][1] = __builtin_amdgcn_mfma_f32_16x16x32_bf16(af[t], bfrag[1][t], acc[rt][1], 0, 0, 0);
        }
    }

    // Epilogue. D layout: col=l15, row=quad*4+reg (+16*rt). Node nd = rows rt in {2nd,2nd+1}.
#pragma unroll
    for (int c2 = 0; c2 < 2; ++c2) {
        float sbv = silu_f(bias[c2]);
#pragma unroll
        for (int nd = 0; nd < 4; ++nd) {
            float p = 0.0f;
#pragma unroll
            for (int h = 0; h < 2; ++h) {
                int rt = 2 * nd + h;
#pragma unroll
                for (int g = 0; g < 4; ++g)
                    p += silu_f(acc[rt][c2][g] + bias[c2]);
            }
            p += __shfl_xor(p, 16);
            p += __shfl_xor(p, 32);
            if (quad == nd) {
                float c = s_cnt[nd];
                float val = (p - (32.0f - c) * sbv) / (c + 1e-5f);
                out[(size_t)(n0 + nd) * 512 + (2 * wid + c2) * 16 + l15] = val;
            }
        }
    }
}

// ---- Kernel 3: dims 128..512. One wave per node; ballot-compacted neighbor list. ----
template<bool USE_WS>
__global__ __launch_bounds__(256) void seg_kernel(
    const int*   __restrict__ an,      // [N]
    const float* __restrict__ nde,     // [N,10]
    const int*   __restrict__ nl,      // [N,32]
    const int*   __restrict__ nmask,   // [N,32]
    const float* __restrict__ semb,    // [100,128]
    const float* __restrict__ temb,    // [100,128]
    const float* __restrict__ sW, const float* __restrict__ sb,
    const float* __restrict__ tW, const float* __restrict__ tb,
    const float* __restrict__ sd_ws,   // [N,64] or null
    const float* __restrict__ td_ws,   // [N,64] or null
    float* __restrict__ out)           // [N,512]
{
    const int tid  = threadIdx.x;
    const int wid  = tid >> 6;
    const int lane = tid & 63;
    const int n    = blockIdx.x * 4 + wid;

    __shared__ int s_idx[4][KK];
    __shared__ int s_aidx[4][KK];

    int j = 0; bool act = false;
    if (lane < KK) {
        j   = nl[n * KK + lane];
        act = (nmask[n * KK + lane] != 0);
    }
    unsigned long long bits = __ballot(act);
    int cnt = (int)__popcll(bits);
    if (act) {
        int rank = (int)__popcll(bits & ((1ull << lane) - 1ull));
        s_idx[wid][rank]  = j;
        s_aidx[wid][rank] = an[j];
    }
    __syncthreads();

    const float invv  = 1.0f / ((float)cnt + 1e-5f);
    const float scale = (float)cnt * invv;
    float* outn = out + (size_t)n * 512;

    // sender dir (128..192), d = lane
    {
        float s = 0.0f;
        if constexpr (USE_WS) {
#pragma unroll 4
            for (int i = 0; i < cnt; ++i)
                s += sd_ws[s_idx[wid][i] * DDIR + lane];
        } else {
            for (int i = 0; i < cnt; ++i) {
                int jj = s_idx[wid][i];
                float a = sb[lane];
#pragma unroll
                for (int q = 0; q < DDIRIN; ++q)
                    a = fmaf(nde[jj * DDIRIN + q], sW[q * DDIR + lane], a);
                s += silu_f(a);
            }
        }
        outn[128 + lane] = s * invv;
    }

    // sender atom (192..320)
    {
        float s0 = 0.0f, s1 = 0.0f;
#pragma unroll 4
        for (int i = 0; i < cnt; ++i) {
            int a = s_aidx[wid][i];
            s0 += semb[a * DD + lane];
            s1 += semb[a * DD + 64 + lane];
        }
        outn[192 + lane] = s0 * invv;
        outn[256 + lane] = s1 * invv;
    }

    // recv dir (320..384)
    {
        float tdv;
        if constexpr (USE_WS) {
            tdv = td_ws[n * DDIR + lane];
        } else {
            float a = tb[lane];
#pragma unroll
            for (int q = 0; q < DDIRIN; ++q)
                a = fmaf(nde[n * DDIRIN + q], tW[q * DDIR + lane], a);
            tdv = silu_f(a);
        }
        outn[320 + lane] = tdv * scale;
    }

    // recv atom (384..512)
    {
        int ann = an[n];
        outn[384 + lane] = temb[ann * DD + lane] * scale;
        outn[448 + lane] = temb[ann * DD + 64 + lane] * scale;
    }
}

extern "C" void kernel_launch(void* const* d_in, const int* in_sizes, int n_in,
                              void* d_out, int out_size, void* d_ws, size_t ws_size,
                              hipStream_t stream) {
    const int*   an    = (const int*)  d_in[0];
    const float* nde   = (const float*)d_in[1];
    const float* edist = (const float*)d_in[2];
    const int*   nl    = (const int*)  d_in[3];
    const int*   nmask = (const int*)  d_in[4];
    const float* semb  = (const float*)d_in[5];
    const float* temb  = (const float*)d_in[6];
    const float* sW    = (const float*)d_in[7];
    const float* sb    = (const float*)d_in[8];
    const float* tW    = (const float*)d_in[9];
    const float* tb    = (const float*)d_in[10];
    const float* dW    = (const float*)d_in[11];
    const float* db    = (const float*)d_in[12];
    float* out = (float*)d_out;

    gemm_kernel<<<NN / 4, 256, 0, stream>>>(edist, nmask, dW, db, out);

    const size_t need = (size_t)NN * DDIR * sizeof(float) * 2;   // 5.12 MB
    if (ws_size >= need) {
        float* sd = (float*)d_ws;
        float* td = sd + (size_t)NN * DDIR;
        dir_kernel<<<(NN * DDIR + 255) / 256, 256, 0, stream>>>(nde, sW, sb, tW, tb, sd, td);
        seg_kernel<true><<<NN / 4, 256, 0, stream>>>(
            an, nde, nl, nmask, semb, temb, sW, sb, tW, tb, sd, td, out);
    } else {
        seg_kernel<false><<<NN / 4, 256, 0, stream>>>(
            an, nde, nl, nmask, semb, temb, sW, sb, tW, tb, nullptr, nullptr, out);
    }
}